// Round 8
// baseline (194.610 us; speedup 1.0000x reference)
//
#include <hip/hip_runtime.h>

// Inputs: [32,3,512,512] f32; pooled grid 128x128 per image.
#define HH 512
#define WW 512
#define PH 128
#define PW 128
#define CC 3

typedef float f32x4 __attribute__((ext_vector_type(4)));

// Kernel 1: g[b,i,j] = (1/48) * sum_{c, 4x4 block} (orig - enh)
// One thread per pooled cell, 2048 blocks (8/CU). NON-TEMPORAL dwordx4 loads
// (nt: no cache allocation -- R6 proved this breaks the 2.79 TB/s cached-read
// clamp). All 24 loads issued back-to-back with no loop-carried dependence,
// then one reduction. Wave reads are 1 KB contiguous per (c,r) step.
__global__ void __launch_bounds__(256)
pool_diff_kernel(const float* __restrict__ orig,
                 const float* __restrict__ enh,
                 float* __restrict__ g, int total) {
    const int idx = blockIdx.x * blockDim.x + threadIdx.x;
    if (idx >= total) return;
    const int j = idx & (PW - 1);
    const int i = (idx >> 7) & (PH - 1);
    const int b = idx >> 14;

    const size_t img  = (size_t)HH * WW;          // 262144
    const size_t base = (size_t)b * CC * img + (size_t)(i * 4) * WW + (size_t)(j * 4);

    f32x4 ov[12], ev[12];
#pragma unroll
    for (int c = 0; c < CC; ++c) {
#pragma unroll
        for (int r = 0; r < 4; ++r) {
            const size_t off = base + (size_t)c * img + (size_t)r * WW;
            ov[c * 4 + r] = __builtin_nontemporal_load((const f32x4*)(orig + off));
        }
    }
#pragma unroll
    for (int c = 0; c < CC; ++c) {
#pragma unroll
        for (int r = 0; r < 4; ++r) {
            const size_t off = base + (size_t)c * img + (size_t)r * WW;
            ev[c * 4 + r] = __builtin_nontemporal_load((const f32x4*)(enh + off));
        }
    }

    float s = 0.0f;
#pragma unroll
    for (int t = 0; t < 12; ++t) {
        s += (ov[t].x - ev[t].x) + (ov[t].y - ev[t].y)
           + (ov[t].z - ev[t].z) + (ov[t].w - ev[t].w);
    }
    g[idx] = s * (1.0f / 48.0f);
}

// Kernel 2: loss[i,j] = sum over {l,r,u,d} of (g[i,j] - g_pad[neighbor])^2
// Zero padding: out-of-bounds neighbor contributes 0 (so diff = g[i,j]).
__global__ void __launch_bounds__(256)
stencil_loss_kernel(const float* __restrict__ g,
                    float* __restrict__ out, int total) {
    int idx = blockIdx.x * blockDim.x + threadIdx.x;
    if (idx >= total) return;
    int j = idx & (PW - 1);
    int i = (idx >> 7) & (PH - 1);

    float c = g[idx];
    float l = (j > 0)      ? g[idx - 1]  : 0.0f;
    float r = (j < PW - 1) ? g[idx + 1]  : 0.0f;
    float u = (i > 0)      ? g[idx - PW] : 0.0f;
    float d = (i < PH - 1) ? g[idx + PW] : 0.0f;

    float dl = c - l, dr = c - r, du = c - u, dd = c - d;
    float res = dl * dl + dr * dr + du * du + dd * dd;
    __builtin_nontemporal_store(res, out + idx);
}

extern "C" void kernel_launch(void* const* d_in, const int* in_sizes, int n_in,
                              void* d_out, int out_size, void* d_ws, size_t ws_size,
                              hipStream_t stream) {
    const float* orig = (const float*)d_in[0];
    const float* enh  = (const float*)d_in[1];
    float* out = (float*)d_out;
    float* g   = (float*)d_ws;  // 32*128*128 floats = 2 MB scratch

    const int batch = in_sizes[0] / (CC * HH * WW);   // 32
    const int total = batch * PH * PW;                // 524288

    const int block = 256;
    const int grid = (total + block - 1) / block;     // 2048

    pool_diff_kernel<<<grid, block, 0, stream>>>(orig, enh, g, total);
    stencil_loss_kernel<<<grid, block, 0, stream>>>(g, out, total);
}